// Round 17
// baseline (1400.581 us; speedup 1.0000x reference)
//
#include <hip/hip_runtime.h>
#include <math.h>

namespace {

typedef __attribute__((ext_vector_type(8))) short short8;
typedef __attribute__((ext_vector_type(4))) float f32x4;

constexpr int kN   = 10000;
constexpr int kE   = 200000;
constexpr int kNT  = 95;
constexpr int kNFD = 480;

__device__ __forceinline__ ushort bf(float f) {
  union { float f; uint u; } c; c.f = f;
  uint r = c.u + 0x7FFF + ((c.u >> 16) & 1);
  return (ushort)(r >> 16);
}
__device__ __forceinline__ float fb(ushort u) {
  union { uint u; float f; } c; c.u = ((uint)u) << 16;
  return c.f;
}
__device__ __forceinline__ uint pk2(float a, float b) {
  return (uint)bf(a) | ((uint)bf(b) << 16);
}

// Fast barrier: orders LDS ops + raw barrier; does NOT drain vmcnt (T4).
__device__ __forceinline__ void fastbar() {
  asm volatile("s_waitcnt lgkmcnt(0)" ::: "memory");
  __builtin_amdgcn_s_barrier();
}

// ---------------------------------------------------------------------------
// Weight repack into MFMA B-fragment layout (N-guarded, NT-paddable).
// ---------------------------------------------------------------------------
__device__ __forceinline__ void packone(int u, const float* We, const float* Ws,
                                        int expStride, int Kreal, int Nstride,
                                        int Nreal, int NT, int NKp, ushort* d) {
  int i = u & 7;
  int lane = (u >> 3) & 63;
  int rest = u >> 9;
  int kc = rest % NKp; rest /= NKp;
  int nt = rest % NT;
  int e  = rest / NT;
  int k = kc*32 + (lane >> 4)*8 + i;
  int n = nt*16 + (lane & 15);
  float v = 0.f;
  if (k < Kreal && n < Nreal) {
    const float* s = (Ws != nullptr && e == 8) ? Ws : (We + (size_t)e*expStride);
    v = s[(size_t)k*Nstride + n];
  }
  d[u] = bf(v);
}

constexpr int PK0   = 0;
constexpr int PK1   = 442368;
constexpr int PK2   = 497664;
constexpr int PKENV = 516096;
constexpr int PKP0  = 544768;
constexpr int PKP1  = 561152;
constexpr int PKP2  = 565248;
constexpr int PKTOT = 566272;

__global__ __launch_bounds__(256)
void pack_k(const float* __restrict__ W0e, const float* __restrict__ W0s,
            const float* __restrict__ W1e, const float* __restrict__ W1s,
            const float* __restrict__ W2e, const float* __restrict__ W2s,
            const float* __restrict__ Wenv, const float* __restrict__ Wp0,
            const float* __restrict__ Wp1, const float* __restrict__ Wp2,
            ushort* __restrict__ dst) {
  int gid = blockIdx.x*256 + threadIdx.x;
  if (gid >= PKTOT) return;
  if (gid < PK1)        packone(gid - PK0,   W0e, W0s, 192*224, 192, 224, 224, 16, 6, dst + PK0);
  else if (gid < PK2)   packone(gid - PK1,   W1e, W1s, 96*64,    96,  64,  64,  4, 3, dst + PK1);
  else if (gid < PKENV) packone(gid - PK2,   W2e, W2s, 48*32,    48,  32,  32,  2, 2, dst + PK2);
  else if (gid < PKP0)  packone(gid - PKENV, Wenv, nullptr, 0,  128, 224, 224, 14, 4, dst + PKENV);
  else if (gid < PKP1)  packone(gid - PKP0,  Wp0, nullptr, 0,   128, 128, 128,  8, 4, dst + PKP0);
  else if (gid < PKP2)  packone(gid - PKP1,  Wp1, nullptr, 0,    64,  64,  64,  4, 2, dst + PKP1);
  else                  packone(gid - PKP2,  Wp2, nullptr, 0,    32,  32,  32,  2, 1, dst + PKP2);
}

// ---------------------------------------------------------------------------
// mgl[x] = dot(mole_globals, Wm[:,x])
// ---------------------------------------------------------------------------
__global__ __launch_bounds__(64)
void mgl_k(const float* __restrict__ mgv, const float* __restrict__ Wm,
           float* __restrict__ mgl) {
  int x = threadIdx.x;
  if (x < 8) {
    float s = 0.f;
    for (int l = 0; l < 128; ++l) s += mgv[l]*Wm[l*8 + x];
    mgl[x] = s;
  }
}

// ---------------------------------------------------------------------------
// CSR build (unchanged).
// ---------------------------------------------------------------------------
__global__ __launch_bounds__(256)
void hist_k(const int* __restrict__ eidx, const int* __restrict__ act,
            int* __restrict__ counts) {
  int e = blockIdx.x*256 + threadIdx.x;
  if (e < kE) atomicAdd(&counts[eidx[act[e]]], 1);
}

__global__ __launch_bounds__(256)
void scan_k(const int* __restrict__ counts, int* __restrict__ rowptr,
            int* __restrict__ cursor) {
  __shared__ int part[256];
  const int t = threadIdx.x;
  const int start = t*40;
  int local = 0;
  for (int i = 0; i < 40; ++i) {
    int idx = start + i;
    if (idx < kN) local += counts[idx];
  }
  part[t] = local;
  __syncthreads();
  for (int ofs = 1; ofs < 256; ofs <<= 1) {
    int v = (t >= ofs) ? part[t - ofs] : 0;
    __syncthreads();
    part[t] += v;
    __syncthreads();
  }
  int run = part[t] - local;
  for (int i = 0; i < 40; ++i) {
    int idx = start + i;
    if (idx < kN) {
      rowptr[idx] = run;
      cursor[idx] = run;
      run += counts[idx];
    }
  }
  if (t == 255) rowptr[kN] = run;
}

__global__ __launch_bounds__(256)
void scatter_k(const int* __restrict__ eidx, const int* __restrict__ act,
               int* __restrict__ cursor, int* __restrict__ elist) {
  int e = blockIdx.x*256 + threadIdx.x;
  if (e < kE) {
    int n = eidx[act[e]];
    int pos = atomicAdd(&cursor[n], 1);
    elist[pos] = e;
  }
}

// ---------------------------------------------------------------------------
// coef_k: softmax gate coefficients per edge.
// ---------------------------------------------------------------------------
__global__ __launch_bounds__(256)
void coef_k(const float* __restrict__ latents, const float* __restrict__ mgl,
            const float* __restrict__ Wg, const int* __restrict__ act,
            float* __restrict__ coefg) {
  __shared__ int aidl[32];
  const int tid = threadIdx.x;
  const int base = blockIdx.x*32;

  if (tid < 32) aidl[tid] = act[base + tid];
  __syncthreads();

  int e = tid >> 3, x = tid & 7;
  const float* lat = latents + (size_t)aidl[e]*128;
  float s = mgl[x];
  for (int l = 0; l < 128; ++l) s += lat[l]*Wg[l*8 + x];
  float mx = s;
  mx = fmaxf(mx, __shfl_xor(mx, 1));
  mx = fmaxf(mx, __shfl_xor(mx, 2));
  mx = fmaxf(mx, __shfl_xor(mx, 4));
  float ex = __expf(s - mx);
  float sm = ex;
  sm += __shfl_xor(sm, 1);
  sm += __shfl_xor(sm, 2);
  sm += __shfl_xor(sm, 4);
  size_t a = base + e;
  coefg[a*9 + x] = ex/sm;
  if (x == 0) coefg[a*9 + 8] = 1.f;
}

// ---------------------------------------------------------------------------
// MFMA GEMM (R8 version, unchanged): used for wenv only.
// ---------------------------------------------------------------------------
constexpr int gemm_smbytes(int K1, int NK, int N, int NEXP) {
  int LDA = K1 + 8;
  int NT = N/16;
  int a = 128*LDA*2;
  int b = NT*NK*1024;
  int u = a > b ? a : b;
  return u + (NEXP > 1 ? 128*NEXP*4 : 0);
}

template<int DIV, int K1, int NK, int N, int NEXP, int EPI, bool AF32>
__global__ __launch_bounds__(512)
void gemm_k(const ushort* __restrict__ A, const float* __restrict__ Af,
            const int* __restrict__ ridx, int strideA,
            const ushort* __restrict__ Bpk, const float* __restrict__ coefg,
            int rowsReal, float norm,
            ushort* __restrict__ outbf, const float* __restrict__ bias,
            const ushort* __restrict__ wenvbf, int WCOL) {
  constexpr int NT  = N/16;
  constexpr int CTW = NT/2;
  constexpr int LDA = K1 + 8;
  constexpr int ABYTES = 128*LDA*2;
  constexpr int BBYTES = NT*NK*1024;
  constexpr int UNI = (ABYTES > BBYTES) ? ABYTES : BBYTES;

  extern __shared__ char smraw[];
  ushort* Asm = (ushort*)smraw;
  float* coefsm = (float*)(smraw + UNI);

  const int tid = threadIdx.x;
  const int row0 = blockIdx.x*128;

  constexpr int C8 = K1/8;
  for (int u = tid; u < 128*C8; u += 512) {
    int r = u / C8, c8 = u - r*C8;
    int gr = row0 + r;
    uint4 v = {0u,0u,0u,0u};
    if (gr < rowsReal) {
      if constexpr (AF32) {
        const float* s = Af + (size_t)(ridx ? ridx[gr] : gr)*strideA + c8*8;
        float4 f0 = *(const float4*)s;
        float4 f1 = *(const float4*)(s + 4);
        v.x = pk2(f0.x, f0.y); v.y = pk2(f0.z, f0.w);
        v.z = pk2(f1.x, f1.y); v.w = pk2(f1.z, f1.w);
      } else {
        v = *(const uint4*)(A + (size_t)gr*strideA + c8*8);
      }
    }
    *(uint4*)(&Asm[r*LDA + c8*8]) = v;
  }
  if constexpr (NEXP > 1) {
    for (int u = tid; u < 128*NEXP; u += 512) {
      int r = u / NEXP, e = u - r*NEXP;
      int a = (row0 + r)/DIV;
      coefsm[r*NEXP + e] = coefg[(size_t)a*NEXP + e];
    }
  }
  __syncthreads();

  const int lane = tid & 63, wid = tid >> 6;
  const int cg = wid & 1, rg = wid >> 1;
  const int rbase = rg*32;
  const int lrow = lane & 15, lkb = lane >> 4;

  short8 af[2][NK];
  #pragma unroll
  for (int rt = 0; rt < 2; ++rt)
    #pragma unroll
    for (int kc = 0; kc < NK; ++kc)
      af[rt][kc] = *(const short8*)(&Asm[(rbase + rt*16 + lrow)*LDA + kc*32 + lkb*8]);

  f32x4 acc[2][CTW];
  #pragma unroll
  for (int rt = 0; rt < 2; ++rt)
    #pragma unroll
    for (int ct = 0; ct < CTW; ++ct)
      acc[rt][ct] = f32x4{0.f,0.f,0.f,0.f};

  __syncthreads();

  union BU { uint4 u; short8 s; };
  uint4* Bsm4 = (uint4*)smraw;
  const uint4* Bg4 = (const uint4*)Bpk;

  for (int e = 0; e < NEXP; ++e) {
    for (int u = tid; u < NT*NK*64; u += 512)
      Bsm4[u] = Bg4[(size_t)e*(NT*NK*64) + u];
    __syncthreads();

    if constexpr (NEXP > 1) {
      float cf[2][4];
      #pragma unroll
      for (int rt = 0; rt < 2; ++rt)
        #pragma unroll
        for (int q = 0; q < 4; ++q)
          cf[rt][q] = coefsm[(rbase + rt*16 + lkb*4 + q)*NEXP + e];
      #pragma unroll
      for (int ct = 0; ct < CTW; ++ct) {
        int nt = cg*CTW + ct;
        f32x4 z[2];
        z[0] = f32x4{0.f,0.f,0.f,0.f};
        z[1] = f32x4{0.f,0.f,0.f,0.f};
        #pragma unroll
        for (int kc = 0; kc < NK; ++kc) {
          BU b; b.u = Bsm4[(nt*NK + kc)*64 + lane];
          z[0] = __builtin_amdgcn_mfma_f32_16x16x32_bf16(af[0][kc], b.s, z[0], 0, 0, 0);
          z[1] = __builtin_amdgcn_mfma_f32_16x16x32_bf16(af[1][kc], b.s, z[1], 0, 0, 0);
        }
        #pragma unroll
        for (int q = 0; q < 4; ++q) {
          acc[0][ct][q] += cf[0][q]*z[0][q];
          acc[1][ct][q] += cf[1][q]*z[1][q];
        }
      }
    } else {
      #pragma unroll
      for (int ct = 0; ct < CTW; ++ct) {
        int nt = cg*CTW + ct;
        #pragma unroll
        for (int kc = 0; kc < NK; ++kc) {
          BU b; b.u = Bsm4[(nt*NK + kc)*64 + lane];
          acc[0][ct] = __builtin_amdgcn_mfma_f32_16x16x32_bf16(af[0][kc], b.s, acc[0][ct], 0, 0, 0);
          acc[1][ct] = __builtin_amdgcn_mfma_f32_16x16x32_bf16(af[1][kc], b.s, acc[1][ct], 0, 0, 0);
        }
      }
    }
    __syncthreads();
  }

  #pragma unroll
  for (int rt = 0; rt < 2; ++rt) {
    #pragma unroll
    for (int ct = 0; ct < CTW; ++ct) {
      #pragma unroll
      for (int q = 0; q < 4; ++q) {
        int gr = row0 + rbase + rt*16 + lkb*4 + q;
        if (gr >= rowsReal) continue;
        int o = (cg*CTW + ct)*16 + lrow;
        float val = acc[rt][ct][q]*norm;
        if constexpr (EPI == 0) {
          outbf[(size_t)gr*N + o] = bf(val);
        } else if constexpr (EPI == 1) {
          float av = (o < 128) ? (val/(1.f + __expf(-val)))
                               : (1.f/(1.f + __expf(-val)));
          outbf[(size_t)gr*N + o] = bf(av);
        } else {
          int a = gr/DIV;
          if (bias != nullptr) val += bias[o];
          float w = fb(wenvbf[(size_t)a*224 + WCOL + o]);
          val *= w*0.22360679774997896f;
          outbf[(size_t)gr*N + o] = bf(val);
        }
      }
    }
  }
}

// ---------------------------------------------------------------------------
// ypv_k<L>: FULLY FUSED y-mix + rotate-back + gating + P-projection.
// Block covers RR whole edge-groups (126 rows for L=1, 125 for L=2, padded
// to 128). Phases: fused rotated-input A build -> 9-expert chunked GEMM ->
// y to LDS -> per-thread rotate+gate A2 frags -> P GEMM (B from L2-hot
// global) -> wenv*RN -> pe store.
// ---------------------------------------------------------------------------
constexpr int ypv_smbytes(int K1, int NK, int NT) {
  int a = 128*(K1 + 8)*2;
  int b = 2*NT*NK*1024;
  int y = 128*(NT*16 + 8)*2;
  int u = a > b ? a : b;
  u = u > y ? u : y;
  return u + 128*9*4;
}

template<int L>
__global__ __launch_bounds__(512, 1)
void ypv_k(const float* __restrict__ nodef, const float* __restrict__ edgef,
           const float* __restrict__ Dm, const int* __restrict__ eidx,
           const int* __restrict__ act, const ushort* __restrict__ Bpk,
           const ushort* __restrict__ Bp, const float* __restrict__ coefg,
           const ushort* __restrict__ t0act, const ushort* __restrict__ wenvbf,
           ushort* __restrict__ peout) {
  constexpr int DIV  = (L == 1) ? 3 : 5;
  constexpr int K1   = (L == 1) ? 96 : 64;
  constexpr int NK   = K1/32;
  constexpr int NT   = (L == 1) ? 4 : 2;
  constexpr int N    = NT*16;                 // 64 / 32
  constexpr int CTW  = NT/2;
  constexpr int LDA  = K1 + 8;
  constexpr int RR   = (L == 1) ? 126 : 125;  // whole DIV-groups per block
  constexpr int DSTR = (L == 1) ? 9 : 25;
  constexpr int WCOL = (L == 1) ? 128 : 192;
  constexpr int NB4  = NT*NK*64;
  constexpr int LDY  = N + 8;
  constexpr int NK2  = N/32;                  // P-GEMM K-chunks: 2 / 1
  constexpr int ABYTES = 128*LDA*2;
  constexpr int BBYTES = 2*NB4*16;
  constexpr int UNI0 = (ABYTES > BBYTES) ? ABYTES : BBYTES;
  constexpr int YBYTES = 128*LDY*2;
  constexpr int UNI = (UNI0 > YBYTES) ? UNI0 : YBYTES;

  const float norm1 = (L == 1) ? 0.10206207261596577f : 0.14433756729740643f;
  const float norm2 = (L == 1) ? 0.125f : 0.17677669529663687f;
  const int rowsTotal = (L == 1) ? 3*kE : 5*kE;

  extern __shared__ char smraw[];
  ushort* Asm = (ushort*)smraw;
  float* coefsm = (float*)(smraw + UNI);
  uint4* Bsm4 = (uint4*)smraw;
  const uint4* Bg4 = (const uint4*)Bpk;

  const int tid = threadIdx.x;
  const int row0 = blockIdx.x*RR;

  // ---- phase 1: fused rotated-input A build ----
  constexpr int C8 = K1/8;
  for (int u = tid; u < 128*C8; u += 512) {
    int r = u / C8, c8 = u - r*C8;
    int c0 = c8*8;
    int gr = row0 + r;
    uint4 v = {0u,0u,0u,0u};
    if (gr < rowsTotal) {
      int a = gr/DIV, mm = gr - a*DIV;
      int cen = eidx[act[a]];
      const float* dd = Dm + (size_t)a*DSTR + mm*DIV;
      if constexpr (L == 1) {
        const float* s = (c8 < 8) ? (nodef + (size_t)cen*kNFD + 128 + c0*3)
                                  : (edgef + (size_t)a*240 + 64 + (c0 - 64)*3);
        float ld[24];
        #pragma unroll
        for (int q = 0; q < 6; ++q)
          *(float4*)(ld + q*4) = *(const float4*)(s + q*4);
        float d0 = dd[0], d1 = dd[1], d2 = dd[2];
        float ov[8];
        #pragma unroll
        for (int j = 0; j < 8; ++j)
          ov[j] = d0*ld[3*j] + d1*ld[3*j + 1] + d2*ld[3*j + 2];
        v.x = pk2(ov[0], ov[1]); v.y = pk2(ov[2], ov[3]);
        v.z = pk2(ov[4], ov[5]); v.w = pk2(ov[6], ov[7]);
      } else {
        if (c0 < 48) {
          const float* s = (c0 < 32) ? (nodef + (size_t)cen*kNFD + 320 + c0*5)
                                     : (edgef + (size_t)a*240 + 160 + (c0 - 32)*5);
          float ld[40];
          #pragma unroll
          for (int q = 0; q < 10; ++q)
            *(float4*)(ld + q*4) = *(const float4*)(s + q*4);
          float d0 = dd[0], d1 = dd[1], d2 = dd[2], d3 = dd[3], d4 = dd[4];
          float ov[8];
          #pragma unroll
          for (int j = 0; j < 8; ++j)
            ov[j] = d0*ld[5*j] + d1*ld[5*j+1] + d2*ld[5*j+2] + d3*ld[5*j+3] + d4*ld[5*j+4];
          v.x = pk2(ov[0], ov[1]); v.y = pk2(ov[2], ov[3]);
          v.z = pk2(ov[4], ov[5]); v.w = pk2(ov[6], ov[7]);
        }
      }
    }
    *(uint4*)(&Asm[r*LDA + c0]) = v;
  }
  for (int u = tid; u < 128*9; u += 512) {
    int r = u/9, e = u - r*9;
    int a = (row0 + r)/DIV;
    coefsm[r*9 + e] = coefg[(size_t)a*9 + e];
  }
  __syncthreads();

  const int lane = tid & 63, wid = tid >> 6;
  const int cg = wid & 1, rg = wid >> 1;
  const int rbase = rg*32;
  const int lrow = lane & 15, lkb = lane >> 4;

  short8 af[2][NK];
  #pragma unroll
  for (int rt = 0; rt < 2; ++rt)
    #pragma unroll
    for (int kc = 0; kc < NK; ++kc)
      af[rt][kc] = *(const short8*)(&Asm[(rbase + rt*16 + lrow)*LDA + kc*32 + lkb*8]);

  f32x4 acc[2][CTW];
  #pragma unroll
  for (int rt = 0; rt < 2; ++rt)
    #pragma unroll
    for (int ct = 0; ct < CTW; ++ct)
      acc[rt][ct] = f32x4{0.f,0.f,0.f,0.f};

  __syncthreads();

  union BU { uint4 u; short8 s; };
  uint4 pf0, pf1;

  // ---- phase 2: 9-expert chunked double-buffered GEMM ----
  if (tid < NB4) pf0 = Bg4[tid];
  if constexpr (NB4 > 512) { if (tid + 512 < NB4) pf1 = Bg4[tid + 512]; }
  if (tid < NB4) Bsm4[tid] = pf0;
  if constexpr (NB4 > 512) { if (tid + 512 < NB4) Bsm4[tid + 512] = pf1; }

  for (int e = 0; e < 9; ++e) {
    fastbar();
    if (e + 1 < 9) {
      const uint4* s = Bg4 + (size_t)(e + 1)*NB4;
      if (tid < NB4) pf0 = s[tid];
      if constexpr (NB4 > 512) { if (tid + 512 < NB4) pf1 = s[tid + 512]; }
    }
    float cf[2][4];
    #pragma unroll
    for (int rt = 0; rt < 2; ++rt)
      #pragma unroll
      for (int q = 0; q < 4; ++q)
        cf[rt][q] = coefsm[(rbase + rt*16 + lkb*4 + q)*9 + e];
    const uint4* bb = Bsm4 + (e & 1)*NB4;
    #pragma unroll
    for (int ct = 0; ct < CTW; ++ct) {
      int nt = cg*CTW + ct;
      f32x4 z0 = {0.f,0.f,0.f,0.f}, z1 = {0.f,0.f,0.f,0.f};
      #pragma unroll
      for (int kc = 0; kc < NK; ++kc) {
        BU b; b.u = bb[(nt*NK + kc)*64 + lane];
        z0 = __builtin_amdgcn_mfma_f32_16x16x32_bf16(af[0][kc], b.s, z0, 0, 0, 0);
        z1 = __builtin_amdgcn_mfma_f32_16x16x32_bf16(af[1][kc], b.s, z1, 0, 0, 0);
      }
      #pragma unroll
      for (int q = 0; q < 4; ++q) {
        acc[0][ct][q] += cf[0][q]*z0[q];
        acc[1][ct][q] += cf[1][q]*z1[q];
      }
    }
    fastbar();
    if (e + 1 < 9) {
      uint4* d = Bsm4 + ((e + 1) & 1)*NB4;
      if (tid < NB4) d[tid] = pf0;
      if constexpr (NB4 > 512) { if (tid + 512 < NB4) d[tid + 512] = pf1; }
    }
  }

  // ---- phase 3: y (normalized) to LDS ----
  ushort* yl = (ushort*)smraw;
  #pragma unroll
  for (int rt = 0; rt < 2; ++rt) {
    #pragma unroll
    for (int ct = 0; ct < CTW; ++ct) {
      int o = (cg*CTW + ct)*16 + lrow;
      #pragma unroll
      for (int q = 0; q < 4; ++q) {
        int r = rbase + rt*16 + lkb*4 + q;
        yl[r*LDY + o] = bf(acc[rt][ct][q]*norm1);
      }
    }
  }
  fastbar();

  // ---- phase 4: per-thread rotate + gate -> A2 fragments ----
  short8 af2[2][NK2];
  #pragma unroll
  for (int rt = 0; rt < 2; ++rt) {
    int r2 = rbase + rt*16 + lrow;
    int gr = row0 + r2;
    bool valid = (r2 < RR) && (gr < rowsTotal);
    float dd[DIV];
    int rb = 0;
    const ushort* gtp = nullptr;
    if (valid) {
      int a = gr/DIV, n = gr - a*DIV;
      rb = r2 - n;
      #pragma unroll
      for (int m = 0; m < DIV; ++m) dd[m] = Dm[(size_t)a*DSTR + n*DIV + m];
      gtp = t0act + (size_t)a*224 + WCOL;
    }
    #pragma unroll
    for (int kc = 0; kc < NK2; ++kc) {
      int c0 = kc*32 + lkb*8;
      short8 frag = {0,0,0,0,0,0,0,0};
      if (valid) {
        short8 gt = *(const short8*)(gtp + c0);
        float ov[8];
        #pragma unroll
        for (int j = 0; j < 8; ++j) ov[j] = 0.f;
        #pragma unroll
        for (int m = 0; m < DIV; ++m) {
          short8 ym = *(const short8*)(&yl[(rb + m)*LDY + c0]);
          #pragma unroll
          for (int j = 0; j < 8; ++j) ov[j] += dd[m]*fb((ushort)ym[j]);
        }
        uint4 pkd;
        pkd.x = pk2(ov[0]*fb((ushort)gt[0]), ov[1]*fb((ushort)gt[1]));
        pkd.y = pk2(ov[2]*fb((ushort)gt[2]), ov[3]*fb((ushort)gt[3]));
        pkd.z = pk2(ov[4]*fb((ushort)gt[4]), ov[5]*fb((ushort)gt[5]));
        pkd.w = pk2(ov[6]*fb((ushort)gt[6]), ov[7]*fb((ushort)gt[7]));
        union { uint4 u; short8 s; } cv; cv.u = pkd;
        frag = cv.s;
      }
      af2[rt][kc] = frag;
    }
  }

  // ---- phase 5: P GEMM (B direct from L2-hot packed global) ----
  const uint4* Bgp = (const uint4*)Bp;
  f32x4 acc2[2][CTW];
  #pragma unroll
  for (int rt = 0; rt < 2; ++rt)
    #pragma unroll
    for (int ct = 0; ct < CTW; ++ct)
      acc2[rt][ct] = f32x4{0.f,0.f,0.f,0.f};

  #pragma unroll
  for (int ct = 0; ct < CTW; ++ct) {
    int nt = cg*CTW + ct;
    #pragma unroll
    for (int kc = 0; kc < NK2; ++kc) {
      BU b; b.u = Bgp[(nt*NK2 + kc)*64 + lane];
      acc2[0][ct] = __builtin_amdgcn_mfma_f32_16x16x32_bf16(af2[0][kc], b.s, acc2[0][ct], 0, 0, 0);
      acc2[1][ct] = __builtin_amdgcn_mfma_f32_16x16x32_bf16(af2[1][kc], b.s, acc2[1][ct], 0, 0, 0);
    }
  }

  // ---- phase 6: wenv * RN -> pe store ----
  #pragma unroll
  for (int rt = 0; rt < 2; ++rt) {
    #pragma unroll
    for (int ct = 0; ct < CTW; ++ct) {
      int o = (cg*CTW + ct)*16 + lrow;
      #pragma unroll
      for (int q = 0; q < 4; ++q) {
        int r2 = rbase + rt*16 + lkb*4 + q;
        int gr = row0 + r2;
        if (r2 >= RR || gr >= rowsTotal) continue;
        int a = gr/DIV;
        float val = acc2[rt][ct][q]*norm2;
        val *= fb(wenvbf[(size_t)a*224 + WCOL + o])*0.22360679774997896f;
        peout[(size_t)gr*N + o] = bf(val);
      }
    }
  }
}

// ---------------------------------------------------------------------------
// t0 chunked-pipeline GEMM with fused input build + fused P0 (unchanged R16).
// ---------------------------------------------------------------------------
constexpr int T0SMB = 55808;

template<int C>
__device__ __forceinline__ void t0_phase(int e, int tid, int lane, int cg,
                                         int rbase, int lkb,
                                         const short8 (&af)[2][6],
                                         f32x4 (&acc)[2][7],
                                         const float* coefsm,
                                         uint4* Bsm4, const uint4* Bg4,
                                         uint4& rg0, uint4& rg1, uint4& rg2) {
  fastbar();
  const bool hasNext = !(e == 8 && C == 3);
  if (hasNext) {
    int ne = e + (C == 3 ? 1 : 0);
    int nc = (C + 1) & 3;
    const uint4* s = Bg4 + (size_t)ne*6144 + (size_t)nc*1536;
    rg0 = s[tid]; rg1 = s[tid + 512]; rg2 = s[tid + 1024];
  }
  float cf[2][4];
  #pragma unroll
  for (int rt = 0; rt < 2; ++rt)
    #pragma unroll
    for (int q = 0; q < 4; ++q)
      cf[rt][q] = coefsm[(rbase + rt*16 + lkb*4 + q)*9 + e];
  union BU { uint4 u; short8 s; };
  const uint4* bb = Bsm4 + (C & 1)*1536;
  {
    f32x4 z0 = {0.f,0.f,0.f,0.f}, z1 = {0.f,0.f,0.f,0.f};
    #pragma unroll
    for (int kc = 0; kc < 6; ++kc) {
      BU b; b.u = bb[(cg*6 + kc)*64 + lane];
      z0 = __builtin_amdgcn_mfma_f32_16x16x32_bf16(af[0][kc], b.s, z0, 0, 0, 0);
      z1 = __builtin_amdgcn_mfma_f32_16x16x32_bf16(af[1][kc], b.s, z1, 0, 0, 0);
    }
    #pragma unroll
    for (int q = 0; q < 4; ++q) {
      acc[0][2*C][q] += cf[0][q]*z0[q];
      acc[1][2*C][q] += cf[1][q]*z1[q];
    }
  }
  if constexpr (2*C + 1 < 7) {
    f32x4 z0 = {0.f,0.f,0.f,0.f}, z1 = {0.f,0.f,0.f,0.f};
    #pragma unroll
    for (int kc = 0; kc < 6; ++kc) {
      BU b; b.u = bb[((2 + cg)*6 + kc)*64 + lane];
      z0 = __builtin_amdgcn_mfma_f32_16x16x32_bf16(af[0][kc], b.s, z0, 0, 0, 0);
      z1 = __builtin_amdgcn_mfma_f32_16x16x32_bf16(af[1][kc], b.s, z1, 0, 0, 0);
    }
    #pragma unroll
    for (int q = 0; q < 4; ++q) {
      acc[0][2*C + 1][q] += cf[0][q]*z0[q];
      acc[1][2*C + 1][q] += cf[1][q]*z1[q];
    }
  }
  fastbar();
  if (hasNext) {
    uint4* d = Bsm4 + ((C + 1) & 1)*1536;
    d[tid] = rg0; d[tid + 512] = rg1; d[tid + 1024] = rg2;
  }
}

__global__ __launch_bounds__(512, 2)
void t0c_k(const float* __restrict__ nodef, const float* __restrict__ edgef,
           const int* __restrict__ eidx, const int* __restrict__ act,
           const ushort* __restrict__ Bpk, const ushort* __restrict__ Bp0,
           const float* __restrict__ coefg, const float* __restrict__ bp0f,
           const ushort* __restrict__ wenvbf,
           ushort* __restrict__ t0act, ushort* __restrict__ pe0) {
  extern __shared__ char smraw[];
  __shared__ int cenl[128];
  ushort* Asm = (ushort*)smraw;
  float* coefsm = (float*)(smraw + 51200);
  uint4* Bsm4 = (uint4*)smraw;
  const uint4* Bg4 = (const uint4*)Bpk;

  const int tid = threadIdx.x;
  const int row0 = blockIdx.x*128;

  if (tid < 128) {
    int gr = row0 + tid;
    cenl[tid] = (gr < kE) ? eidx[act[gr]] : 0;
  }
  __syncthreads();

  for (int u = tid; u < 128*24; u += 512) {
    int r = u/24, g = u - r*24;
    int c0 = g*8;
    int gr = row0 + r;
    uint4 v = {0u,0u,0u,0u};
    if (gr < kE) {
      const float* s = (g < 16) ? (nodef + (size_t)cenl[r]*kNFD + c0)
                                : (edgef + (size_t)gr*240 + (c0 - 128));
      float4 f0 = *(const float4*)s;
      float4 f1 = *(const float4*)(s + 4);
      v.x = pk2(f0.x, f0.y); v.y = pk2(f0.z, f0.w);
      v.z = pk2(f1.x, f1.y); v.w = pk2(f1.z, f1.w);
    }
    *(uint4*)(&Asm[r*200 + c0]) = v;
  }
  for (int u = tid; u < 128*9; u += 512) {
    int r = u/9, e = u - r*9;
    coefsm[r*9 + e] = coefg[(size_t)(row0 + r)*9 + e];
  }
  __syncthreads();

  const int lane = tid & 63, wid = tid >> 6;
  const int cg = wid & 1, rg = wid >> 1;
  const int rbase = rg*32;
  const int lrow = lane & 15, lkb = lane >> 4;

  short8 af[2][6];
  #pragma unroll
  for (int rt = 0; rt < 2; ++rt)
    #pragma unroll
    for (int kc = 0; kc < 6; ++kc)
      af[rt][kc] = *(const short8*)(&Asm[(rbase + rt*16 + lrow)*200 + kc*32 + lkb*8]);

  f32x4 acc[2][7];
  #pragma unroll
  for (int rt = 0; rt < 2; ++rt)
    #pragma unroll
    for (int ct = 0; ct < 7; ++ct)
      acc[rt][ct] = f32x4{0.f,0.f,0.f,0.f};

  __syncthreads();

  uint4 rg0, rg1, rg2;
  { const uint4* s = Bg4; rg0 = s[tid]; rg1 = s[tid + 512]; rg2 = s[tid + 1024]; }
  { uint4* d = Bsm4;      d[tid] = rg0; d[tid + 512] = rg1; d[tid + 1024] = rg2; }

  for (int e = 0; e < 9; ++e) {
    t0_phase<0>(e, tid, lane, cg, rbase, lkb, af, acc, coefsm, Bsm4, Bg4, rg0, rg1, rg2);
    t0_phase<1>(e, tid, lane, cg, rbase, lkb, af, acc, coefsm, Bsm4, Bg4, rg0, rg1, rg2);
    t0_phase<2>(e, tid, lane, cg, rbase, lkb, af, acc, coefsm, Bsm4, Bg4, rg0, rg1, rg2);
    t0_phase<3>(e, tid, lane, cg, rbase, lkb, af, acc, coefsm, Bsm4, Bg4, rg0, rg1, rg2);
  }

  ushort* A2 = (ushort*)smraw;
  #pragma unroll
  for (int rt = 0; rt < 2; ++rt) {
    #pragma unroll
    for (int ct = 0; ct < 7; ++ct) {
      int o = (2*ct + cg)*16 + lrow;
      #pragma unroll
      for (int q = 0; q < 4; ++q) {
        int rloc = rbase + rt*16 + lkb*4 + q;
        int gr = row0 + rloc;
        float val = acc[rt][ct][q]*0.07216878364870323f;
        if (o < 128) {
          A2[rloc*136 + o] = bf(val/(1.f + __expf(-val)));
        } else if (gr < kE) {
          t0act[(size_t)gr*224 + o] = bf(1.f/(1.f + __expf(-val)));
        }
      }
    }
  }
  fastbar();

  short8 af2[2][4];
  #pragma unroll
  for (int rt = 0; rt < 2; ++rt)
    #pragma unroll
    for (int kc = 0; kc < 4; ++kc)
      af2[rt][kc] = *(const short8*)(&A2[(rbase + rt*16 + lrow)*136 + kc*32 + lkb*8]);

  union BU { uint4 u; short8 s; };
  const uint4* Bg0 = (const uint4*)Bp0;
  f32x4 acc2[2][4];
  #pragma unroll
  for (int rt = 0; rt < 2; ++rt)
    #pragma unroll
    for (int ct = 0; ct < 4; ++ct)
      acc2[rt][ct] = f32x4{0.f,0.f,0.f,0.f};

  #pragma unroll
  for (int ct = 0; ct < 4; ++ct) {
    int nt = cg*4 + ct;
    #pragma unroll
    for (int kc = 0; kc < 4; ++kc) {
      BU b; b.u = Bg0[(nt*4 + kc)*64 + lane];
      acc2[0][ct] = __builtin_amdgcn_mfma_f32_16x16x32_bf16(af2[0][kc], b.s, acc2[0][ct], 0, 0, 0);
      acc2[1][ct] = __builtin_amdgcn_mfma_f32_16x16x32_bf16(af2[1][kc], b.s, acc2[1][ct], 0, 0, 0);
    }
  }

  #pragma unroll
  for (int rt = 0; rt < 2; ++rt) {
    #pragma unroll
    for (int ct = 0; ct < 4; ++ct) {
      int o = (cg*4 + ct)*16 + lrow;
      float bia = bp0f[o];
      #pragma unroll
      for (int q = 0; q < 4; ++q) {
        int gr = row0 + rbase + rt*16 + lkb*4 + q;
        if (gr >= kE) continue;
        float v = acc2[rt][ct][q]*0.08838834764831845f + bia;
        v *= fb(wenvbf[(size_t)gr*224 + o])*0.22360679774997896f;
        pe0[(size_t)gr*128 + o] = bf(v);
      }
    }
  }
}

// ---------------------------------------------------------------------------
// Fused CSR gather + node finalize (unchanged).
// ---------------------------------------------------------------------------
__global__ __launch_bounds__(256)
void gather_k(const float* __restrict__ nodef, const float* __restrict__ onehot,
              const float* __restrict__ Woh0, const float* __restrict__ Woh1,
              const float* __restrict__ Woh2,
              const int* __restrict__ rowptr, const int* __restrict__ elist,
              const ushort* __restrict__ pe0, const ushort* __restrict__ pe1,
              const ushort* __restrict__ pe2, float* __restrict__ out) {
  __shared__ int tn;
  const int n = blockIdx.x;
  const int t = threadIdx.x;
  if (t < kNT && onehot[(size_t)n*kNT + t] > 0.5f) tn = t;
  __syncthreads();
  const int ty = tn;
  const int r0 = rowptr[n], r1 = rowptr[n + 1];
  const float c_old = 0.8944271909999159f;
  const float c_new = 0.4472135954999579f;
  const float invs  = 0.10259783520851541f;

  for (int j = t; j < kNFD; j += 256) {
    int kind, row_m, col;
    if (j < 128)       { kind = 0; row_m = 0; col = j; }
    else if (j < 320)  { int jj = j - 128; col = jj/3; row_m = jj - col*3; kind = 1; }
    else               { int jj = j - 320; col = jj/5; row_m = jj - col*5; kind = 2; }

    float s = 0.f;
    for (int d = r0; d < r1; ++d) {
      int e = elist[d];
      ushort v;
      if (kind == 0)      v = pe0[(size_t)e*128 + col];
      else if (kind == 1) v = pe1[((size_t)e*3 + row_m)*64 + col];
      else                v = pe2[((size_t)e*5 + row_m)*32 + col];
      s += fb(v);
    }

    size_t idx = (size_t)n*kNFD + j;
    float h = c_old*nodef[idx] + c_new*s;
    float f;
    if (j < 128)      f = Woh0[j*kNT + ty];
    else if (j < 320) f = Woh1[((j - 128)/3)*kNT + ty];
    else              f = Woh2[((j - 320)/5)*kNT + ty];
    out[idx] = h*(1.f + f*invs);
  }
}

// workspace layout (bytes)
constexpr size_t OFF_CNT  = 0;
constexpr size_t OFF_CUR  = 40000;
constexpr size_t OFF_RP   = 80000;
constexpr size_t OFF_EL   = 120064;
constexpr size_t OFF_PACK = 1000000;
constexpr size_t OFF_COEF = 19200000;
constexpr size_t OFF_MGL  = 26402304;
constexpr size_t OFF_PE0  = 168031232;
constexpr size_t OFF_PE1  = 219264000;
constexpr size_t OFF_WENV = 347272192;
constexpr size_t OFF_T0A  = 436900864;
constexpr size_t OFF_PE2  = 526529536;

} // namespace

extern "C" void kernel_launch(void* const* d_in, const int* in_sizes, int n_in,
                              void* d_out, int out_size, void* d_ws, size_t ws_size,
                              hipStream_t stream) {
  (void)in_sizes; (void)n_in; (void)out_size; (void)ws_size;
  const float* latents = (const float*)d_in[0];
  const float* nodef   = (const float*)d_in[1];
  const float* edgef   = (const float*)d_in[2];
  const float* mg      = (const float*)d_in[4];
  const float* D1      = (const float*)d_in[5];
  const float* D2      = (const float*)d_in[6];
  const float* onehot  = (const float*)d_in[7];
  const float* Wg      = (const float*)d_in[8];
  const float* Wm      = (const float*)d_in[9];
  const float* W0e     = (const float*)d_in[10];
  const float* W0s     = (const float*)d_in[11];
  const float* W1e     = (const float*)d_in[12];
  const float* W1s     = (const float*)d_in[13];
  const float* W2e     = (const float*)d_in[14];
  const float* W2s     = (const float*)d_in[15];
  const float* Wp0     = (const float*)d_in[16];
  const float* bp0     = (const float*)d_in[17];
  const float* Wp1     = (const float*)d_in[18];
  const float* Wp2     = (const float*)d_in[19];
  const float* Wenv    = (const float*)d_in[20];
  const float* Woh0    = (const float*)d_in[21];
  const float* Woh1    = (const float*)d_in[22];
  const float* Woh2    = (const float*)d_in[23];
  const int* eidx      = (const int*)d_in[25];
  const int* act       = (const int*)d_in[26];

  char* ws = (char*)d_ws;
  int*    cnt   = (int*)(ws + OFF_CNT);
  int*    cur   = (int*)(ws + OFF_CUR);
  int*    rp    = (int*)(ws + OFF_RP);
  int*    el    = (int*)(ws + OFF_EL);
  ushort* pk    = (ushort*)(ws + OFF_PACK);
  float*  coef  = (float*)(ws + OFF_COEF);
  float*  mgl   = (float*)(ws + OFF_MGL);
  ushort* wenv  = (ushort*)(ws + OFF_WENV);
  ushort* t0act = (ushort*)(ws + OFF_T0A);
  ushort* pe0   = (ushort*)(ws + OFF_PE0);
  ushort* pe1   = (ushort*)(ws + OFF_PE1);
  ushort* pe2   = (ushort*)(ws + OFF_PE2);
  float*  out   = (float*)d_out;

  // ---- CSR build ----
  hipMemsetAsync(cnt, 0, kN*sizeof(int), stream);
  hist_k<<<(kE + 255)/256, 256, 0, stream>>>(eidx, act, cnt);
  scan_k<<<1, 256, 0, stream>>>(cnt, rp, cur);
  scatter_k<<<(kE + 255)/256, 256, 0, stream>>>(eidx, act, cur, el);

  pack_k<<<(PKTOT + 255)/256, 256, 0, stream>>>(W0e, W0s, W1e, W1s, W2e, W2s,
                                                Wenv, Wp0, Wp1, Wp2, pk);
  mgl_k<<<1, 64, 0, stream>>>(mg, Wm, mgl);
  coef_k<<<kE/32, 256, 0, stream>>>(latents, mgl, Wg, act, coef);

  // wenv = latents[act] @ Wenv / sqrt(128)
  {
    auto kp = gemm_k<1,128,4,224,1,0,true>;
    int smb = gemm_smbytes(128,4,224,1);
    hipFuncSetAttribute((const void*)kp, hipFuncAttributeMaxDynamicSharedMemorySize, smb);
    kp<<<1563, 512, smb, stream>>>(
        nullptr, latents, act, 128, pk + PKENV, nullptr, kE, 0.08838834764831845f,
        wenv, nullptr, nullptr, 0);
  }

  // t0 = mix0 with fused input build + fused P0 epilogue (needs coef, wenv)
  {
    hipFuncSetAttribute((const void*)t0c_k,
                        hipFuncAttributeMaxDynamicSharedMemorySize, T0SMB);
    t0c_k<<<1563, 512, T0SMB, stream>>>(nodef, edgef, eidx, act,
                                        pk + PK0, pk + PKP0, coef,
                                        bp0, wenv, t0act, pe0);
  }

  // ypv<1>: fused y1-mix + rotate-back + gating + P1 -> pe1
  {
    auto kp = ypv_k<1>;
    int smb = ypv_smbytes(96, 3, 4);
    hipFuncSetAttribute((const void*)kp, hipFuncAttributeMaxDynamicSharedMemorySize, smb);
    int grid = (3*kE + 125)/126;
    kp<<<grid, 512, smb, stream>>>(nodef, edgef, D1, eidx, act,
                                   pk + PK1, pk + PKP1, coef, t0act, wenv, pe1);
  }
  // ypv<2>: fused y2-mix + rotate-back + gating + P2 -> pe2
  {
    auto kp = ypv_k<2>;
    int smb = ypv_smbytes(64, 2, 2);
    hipFuncSetAttribute((const void*)kp, hipFuncAttributeMaxDynamicSharedMemorySize, smb);
    int grid = (5*kE + 124)/125;
    kp<<<grid, 512, smb, stream>>>(nodef, edgef, D2, eidx, act,
                                   pk + PK2, pk + PKP2, coef, t0act, wenv, pe2);
  }

  gather_k<<<kN, 256, 0, stream>>>(nodef, onehot, Woh0, Woh1, Woh2,
                                   rp, el, pe0, pe1, pe2, out);
}

// Round 18
// 1269.878 us; speedup vs baseline: 1.1029x; 1.1029x over previous
//
#include <hip/hip_runtime.h>
#include <math.h>

namespace {

typedef __attribute__((ext_vector_type(8))) short short8;
typedef __attribute__((ext_vector_type(4))) float f32x4;

constexpr int kN   = 10000;
constexpr int kE   = 200000;
constexpr int kNT  = 95;
constexpr int kNFD = 480;

__device__ __forceinline__ ushort bf(float f) {
  union { float f; uint u; } c; c.f = f;
  uint r = c.u + 0x7FFF + ((c.u >> 16) & 1);
  return (ushort)(r >> 16);
}
__device__ __forceinline__ float fb(ushort u) {
  union { uint u; float f; } c; c.u = ((uint)u) << 16;
  return c.f;
}
__device__ __forceinline__ uint pk2(float a, float b) {
  return (uint)bf(a) | ((uint)bf(b) << 16);
}

// Fast barrier: orders LDS ops + raw barrier; does NOT drain vmcnt (T4).
__device__ __forceinline__ void fastbar() {
  asm volatile("s_waitcnt lgkmcnt(0)" ::: "memory");
  __builtin_amdgcn_s_barrier();
}

// ---------------------------------------------------------------------------
// Weight repack into MFMA B-fragment layout (N-guarded, NT-paddable).
// ---------------------------------------------------------------------------
__device__ __forceinline__ void packone(int u, const float* We, const float* Ws,
                                        int expStride, int Kreal, int Nstride,
                                        int Nreal, int NT, int NKp, ushort* d) {
  int i = u & 7;
  int lane = (u >> 3) & 63;
  int rest = u >> 9;
  int kc = rest % NKp; rest /= NKp;
  int nt = rest % NT;
  int e  = rest / NT;
  int k = kc*32 + (lane >> 4)*8 + i;
  int n = nt*16 + (lane & 15);
  float v = 0.f;
  if (k < Kreal && n < Nreal) {
    const float* s = (Ws != nullptr && e == 8) ? Ws : (We + (size_t)e*expStride);
    v = s[(size_t)k*Nstride + n];
  }
  d[u] = bf(v);
}

constexpr int PK0   = 0;
constexpr int PK1   = 442368;
constexpr int PK2   = 497664;
constexpr int PKENV = 516096;
constexpr int PKP0  = 544768;
constexpr int PKP1  = 561152;
constexpr int PKP2  = 565248;
constexpr int PKTOT = 566272;

__global__ __launch_bounds__(256)
void pack_k(const float* __restrict__ W0e, const float* __restrict__ W0s,
            const float* __restrict__ W1e, const float* __restrict__ W1s,
            const float* __restrict__ W2e, const float* __restrict__ W2s,
            const float* __restrict__ Wenv, const float* __restrict__ Wp0,
            const float* __restrict__ Wp1, const float* __restrict__ Wp2,
            ushort* __restrict__ dst) {
  int gid = blockIdx.x*256 + threadIdx.x;
  if (gid >= PKTOT) return;
  if (gid < PK1)        packone(gid - PK0,   W0e, W0s, 192*224, 192, 224, 224, 16, 6, dst + PK0);
  else if (gid < PK2)   packone(gid - PK1,   W1e, W1s, 96*64,    96,  64,  64,  4, 3, dst + PK1);
  else if (gid < PKENV) packone(gid - PK2,   W2e, W2s, 48*32,    48,  32,  32,  2, 2, dst + PK2);
  else if (gid < PKP0)  packone(gid - PKENV, Wenv, nullptr, 0,  128, 224, 224, 14, 4, dst + PKENV);
  else if (gid < PKP1)  packone(gid - PKP0,  Wp0, nullptr, 0,   128, 128, 128,  8, 4, dst + PKP0);
  else if (gid < PKP2)  packone(gid - PKP1,  Wp1, nullptr, 0,    64,  64,  64,  4, 2, dst + PKP1);
  else                  packone(gid - PKP2,  Wp2, nullptr, 0,    32,  32,  32,  2, 1, dst + PKP2);
}

// ---------------------------------------------------------------------------
// mgl[x] = dot(mole_globals, Wm[:,x])
// ---------------------------------------------------------------------------
__global__ __launch_bounds__(64)
void mgl_k(const float* __restrict__ mgv, const float* __restrict__ Wm,
           float* __restrict__ mgl) {
  int x = threadIdx.x;
  if (x < 8) {
    float s = 0.f;
    for (int l = 0; l < 128; ++l) s += mgv[l]*Wm[l*8 + x];
    mgl[x] = s;
  }
}

// ---------------------------------------------------------------------------
// CSR build (unchanged).
// ---------------------------------------------------------------------------
__global__ __launch_bounds__(256)
void hist_k(const int* __restrict__ eidx, const int* __restrict__ act,
            int* __restrict__ counts) {
  int e = blockIdx.x*256 + threadIdx.x;
  if (e < kE) atomicAdd(&counts[eidx[act[e]]], 1);
}

__global__ __launch_bounds__(256)
void scan_k(const int* __restrict__ counts, int* __restrict__ rowptr,
            int* __restrict__ cursor) {
  __shared__ int part[256];
  const int t = threadIdx.x;
  const int start = t*40;
  int local = 0;
  for (int i = 0; i < 40; ++i) {
    int idx = start + i;
    if (idx < kN) local += counts[idx];
  }
  part[t] = local;
  __syncthreads();
  for (int ofs = 1; ofs < 256; ofs <<= 1) {
    int v = (t >= ofs) ? part[t - ofs] : 0;
    __syncthreads();
    part[t] += v;
    __syncthreads();
  }
  int run = part[t] - local;
  for (int i = 0; i < 40; ++i) {
    int idx = start + i;
    if (idx < kN) {
      rowptr[idx] = run;
      cursor[idx] = run;
      run += counts[idx];
    }
  }
  if (t == 255) rowptr[kN] = run;
}

__global__ __launch_bounds__(256)
void scatter_k(const int* __restrict__ eidx, const int* __restrict__ act,
               int* __restrict__ cursor, int* __restrict__ elist) {
  int e = blockIdx.x*256 + threadIdx.x;
  if (e < kE) {
    int n = eidx[act[e]];
    int pos = atomicAdd(&cursor[n], 1);
    elist[pos] = e;
  }
}

// ---------------------------------------------------------------------------
// coef_k: softmax gate coefficients per edge.
// ---------------------------------------------------------------------------
__global__ __launch_bounds__(256)
void coef_k(const float* __restrict__ latents, const float* __restrict__ mgl,
            const float* __restrict__ Wg, const int* __restrict__ act,
            float* __restrict__ coefg) {
  __shared__ int aidl[32];
  const int tid = threadIdx.x;
  const int base = blockIdx.x*32;

  if (tid < 32) aidl[tid] = act[base + tid];
  __syncthreads();

  int e = tid >> 3, x = tid & 7;
  const float* lat = latents + (size_t)aidl[e]*128;
  float s = mgl[x];
  for (int l = 0; l < 128; ++l) s += lat[l]*Wg[l*8 + x];
  float mx = s;
  mx = fmaxf(mx, __shfl_xor(mx, 1));
  mx = fmaxf(mx, __shfl_xor(mx, 2));
  mx = fmaxf(mx, __shfl_xor(mx, 4));
  float ex = __expf(s - mx);
  float sm = ex;
  sm += __shfl_xor(sm, 1);
  sm += __shfl_xor(sm, 2);
  sm += __shfl_xor(sm, 4);
  size_t a = base + e;
  coefg[a*9 + x] = ex/sm;
  if (x == 0) coefg[a*9 + 8] = 1.f;
}

// ---------------------------------------------------------------------------
// MFMA GEMM (R8 version, unchanged): used for wenv.
// ---------------------------------------------------------------------------
constexpr int gemm_smbytes(int K1, int NK, int N, int NEXP) {
  int LDA = K1 + 8;
  int NT = N/16;
  int a = 128*LDA*2;
  int b = NT*NK*1024;
  int u = a > b ? a : b;
  return u + (NEXP > 1 ? 128*NEXP*4 : 0);
}

template<int DIV, int K1, int NK, int N, int NEXP, int EPI, bool AF32>
__global__ __launch_bounds__(512)
void gemm_k(const ushort* __restrict__ A, const float* __restrict__ Af,
            const int* __restrict__ ridx, int strideA,
            const ushort* __restrict__ Bpk, const float* __restrict__ coefg,
            int rowsReal, float norm,
            ushort* __restrict__ outbf, const float* __restrict__ bias,
            const ushort* __restrict__ wenvbf, int WCOL) {
  constexpr int NT  = N/16;
  constexpr int CTW = NT/2;
  constexpr int LDA = K1 + 8;
  constexpr int ABYTES = 128*LDA*2;
  constexpr int BBYTES = NT*NK*1024;
  constexpr int UNI = (ABYTES > BBYTES) ? ABYTES : BBYTES;

  extern __shared__ char smraw[];
  ushort* Asm = (ushort*)smraw;
  float* coefsm = (float*)(smraw + UNI);

  const int tid = threadIdx.x;
  const int row0 = blockIdx.x*128;

  constexpr int C8 = K1/8;
  for (int u = tid; u < 128*C8; u += 512) {
    int r = u / C8, c8 = u - r*C8;
    int gr = row0 + r;
    uint4 v = {0u,0u,0u,0u};
    if (gr < rowsReal) {
      if constexpr (AF32) {
        const float* s = Af + (size_t)(ridx ? ridx[gr] : gr)*strideA + c8*8;
        float4 f0 = *(const float4*)s;
        float4 f1 = *(const float4*)(s + 4);
        v.x = pk2(f0.x, f0.y); v.y = pk2(f0.z, f0.w);
        v.z = pk2(f1.x, f1.y); v.w = pk2(f1.z, f1.w);
      } else {
        v = *(const uint4*)(A + (size_t)gr*strideA + c8*8);
      }
    }
    *(uint4*)(&Asm[r*LDA + c8*8]) = v;
  }
  if constexpr (NEXP > 1) {
    for (int u = tid; u < 128*NEXP; u += 512) {
      int r = u / NEXP, e = u - r*NEXP;
      int a = (row0 + r)/DIV;
      coefsm[r*NEXP + e] = coefg[(size_t)a*NEXP + e];
    }
  }
  __syncthreads();

  const int lane = tid & 63, wid = tid >> 6;
  const int cg = wid & 1, rg = wid >> 1;
  const int rbase = rg*32;
  const int lrow = lane & 15, lkb = lane >> 4;

  short8 af[2][NK];
  #pragma unroll
  for (int rt = 0; rt < 2; ++rt)
    #pragma unroll
    for (int kc = 0; kc < NK; ++kc)
      af[rt][kc] = *(const short8*)(&Asm[(rbase + rt*16 + lrow)*LDA + kc*32 + lkb*8]);

  f32x4 acc[2][CTW];
  #pragma unroll
  for (int rt = 0; rt < 2; ++rt)
    #pragma unroll
    for (int ct = 0; ct < CTW; ++ct)
      acc[rt][ct] = f32x4{0.f,0.f,0.f,0.f};

  __syncthreads();

  union BU { uint4 u; short8 s; };
  uint4* Bsm4 = (uint4*)smraw;
  const uint4* Bg4 = (const uint4*)Bpk;

  for (int e = 0; e < NEXP; ++e) {
    for (int u = tid; u < NT*NK*64; u += 512)
      Bsm4[u] = Bg4[(size_t)e*(NT*NK*64) + u];
    __syncthreads();

    if constexpr (NEXP > 1) {
      float cf[2][4];
      #pragma unroll
      for (int rt = 0; rt < 2; ++rt)
        #pragma unroll
        for (int q = 0; q < 4; ++q)
          cf[rt][q] = coefsm[(rbase + rt*16 + lkb*4 + q)*NEXP + e];
      #pragma unroll
      for (int ct = 0; ct < CTW; ++ct) {
        int nt = cg*CTW + ct;
        f32x4 z[2];
        z[0] = f32x4{0.f,0.f,0.f,0.f};
        z[1] = f32x4{0.f,0.f,0.f,0.f};
        #pragma unroll
        for (int kc = 0; kc < NK; ++kc) {
          BU b; b.u = Bsm4[(nt*NK + kc)*64 + lane];
          z[0] = __builtin_amdgcn_mfma_f32_16x16x32_bf16(af[0][kc], b.s, z[0], 0, 0, 0);
          z[1] = __builtin_amdgcn_mfma_f32_16x16x32_bf16(af[1][kc], b.s, z[1], 0, 0, 0);
        }
        #pragma unroll
        for (int q = 0; q < 4; ++q) {
          acc[0][ct][q] += cf[0][q]*z[0][q];
          acc[1][ct][q] += cf[1][q]*z[1][q];
        }
      }
    } else {
      #pragma unroll
      for (int ct = 0; ct < CTW; ++ct) {
        int nt = cg*CTW + ct;
        #pragma unroll
        for (int kc = 0; kc < NK; ++kc) {
          BU b; b.u = Bsm4[(nt*NK + kc)*64 + lane];
          acc[0][ct] = __builtin_amdgcn_mfma_f32_16x16x32_bf16(af[0][kc], b.s, acc[0][ct], 0, 0, 0);
          acc[1][ct] = __builtin_amdgcn_mfma_f32_16x16x32_bf16(af[1][kc], b.s, acc[1][ct], 0, 0, 0);
        }
      }
    }
    __syncthreads();
  }

  #pragma unroll
  for (int rt = 0; rt < 2; ++rt) {
    #pragma unroll
    for (int ct = 0; ct < CTW; ++ct) {
      #pragma unroll
      for (int q = 0; q < 4; ++q) {
        int gr = row0 + rbase + rt*16 + lkb*4 + q;
        if (gr >= rowsReal) continue;
        int o = (cg*CTW + ct)*16 + lrow;
        float val = acc[rt][ct][q]*norm;
        if constexpr (EPI == 0) {
          outbf[(size_t)gr*N + o] = bf(val);
        } else if constexpr (EPI == 1) {
          float av = (o < 128) ? (val/(1.f + __expf(-val)))
                               : (1.f/(1.f + __expf(-val)));
          outbf[(size_t)gr*N + o] = bf(av);
        } else {
          int a = gr/DIV;
          if (bias != nullptr) val += bias[o];
          float w = fb(wenvbf[(size_t)a*224 + WCOL + o]);
          val *= w*0.22360679774997896f;
          outbf[(size_t)gr*N + o] = bf(val);
        }
      }
    }
  }
}

// ---------------------------------------------------------------------------
// pv_k<L>: P1/P2 GEMM with fused rotate-back + gating A-stage.
// ---------------------------------------------------------------------------
template<int L>
__global__ __launch_bounds__(512)
void pv_k(const ushort* __restrict__ y, const ushort* __restrict__ t0act,
          const float* __restrict__ Dm, const ushort* __restrict__ Bpk,
          int rowsReal, float norm, const ushort* __restrict__ wenvbf,
          ushort* __restrict__ peout) {
  constexpr int DIV = (L == 1) ? 3 : 5;
  constexpr int K1  = (L == 1) ? 64 : 32;
  constexpr int NK  = K1/32;
  constexpr int N   = K1;
  constexpr int NT  = N/16;
  constexpr int CTW = NT/2;
  constexpr int LDA = K1 + 8;
  constexpr int WCOL = (L == 1) ? 128 : 192;
  constexpr int DSTR = (L == 1) ? 9 : 25;

  extern __shared__ char smraw[];
  ushort* Asm = (ushort*)smraw;

  const int tid = threadIdx.x;
  const int row0 = blockIdx.x*128;

  constexpr int C8 = K1/8;
  for (int u = tid; u < 128*C8; u += 512) {
    int r = u / C8, c8 = u - r*C8;
    int c0 = c8*8;
    int gr = row0 + r;
    uint4 v = {0u,0u,0u,0u};
    if (gr < rowsReal) {
      int a = gr/DIV, n = gr - a*DIV;
      const float* dd = Dm + (size_t)a*DSTR + n*DIV;
      short8 gt = *(const short8*)(t0act + (size_t)a*224 + WCOL + c0);
      float ov[8];
      if constexpr (L == 1) {
        short8 m0 = *(const short8*)(y + ((size_t)a*3 + 0)*64 + c0);
        short8 m1 = *(const short8*)(y + ((size_t)a*3 + 1)*64 + c0);
        short8 m2 = *(const short8*)(y + ((size_t)a*3 + 2)*64 + c0);
        float d0 = dd[0], d1 = dd[1], d2 = dd[2];
        #pragma unroll
        for (int j = 0; j < 8; ++j) {
          float s = d0*fb((ushort)m0[j]) + d1*fb((ushort)m1[j]) + d2*fb((ushort)m2[j]);
          ov[j] = s*fb((ushort)gt[j]);
        }
      } else {
        short8 m0 = *(const short8*)(y + ((size_t)a*5 + 0)*32 + c0);
        short8 m1 = *(const short8*)(y + ((size_t)a*5 + 1)*32 + c0);
        short8 m2 = *(const short8*)(y + ((size_t)a*5 + 2)*32 + c0);
        short8 m3 = *(const short8*)(y + ((size_t)a*5 + 3)*32 + c0);
        short8 m4 = *(const short8*)(y + ((size_t)a*5 + 4)*32 + c0);
        float d0 = dd[0], d1 = dd[1], d2 = dd[2], d3 = dd[3], d4 = dd[4];
        #pragma unroll
        for (int j = 0; j < 8; ++j) {
          float s = d0*fb((ushort)m0[j]) + d1*fb((ushort)m1[j])
                  + d2*fb((ushort)m2[j]) + d3*fb((ushort)m3[j])
                  + d4*fb((ushort)m4[j]);
          ov[j] = s*fb((ushort)gt[j]);
        }
      }
      v.x = pk2(ov[0], ov[1]); v.y = pk2(ov[2], ov[3]);
      v.z = pk2(ov[4], ov[5]); v.w = pk2(ov[6], ov[7]);
    }
    *(uint4*)(&Asm[r*LDA + c0]) = v;
  }
  __syncthreads();

  const int lane = tid & 63, wid = tid >> 6;
  const int cg = wid & 1, rg = wid >> 1;
  const int rbase = rg*32;
  const int lrow = lane & 15, lkb = lane >> 4;

  short8 af[2][NK];
  #pragma unroll
  for (int rt = 0; rt < 2; ++rt)
    #pragma unroll
    for (int kc = 0; kc < NK; ++kc)
      af[rt][kc] = *(const short8*)(&Asm[(rbase + rt*16 + lrow)*LDA + kc*32 + lkb*8]);

  f32x4 acc[2][CTW];
  #pragma unroll
  for (int rt = 0; rt < 2; ++rt)
    #pragma unroll
    for (int ct = 0; ct < CTW; ++ct)
      acc[rt][ct] = f32x4{0.f,0.f,0.f,0.f};

  __syncthreads();

  union BU { uint4 u; short8 s; };
  uint4* Bsm4 = (uint4*)smraw;
  const uint4* Bg4 = (const uint4*)Bpk;

  for (int u = tid; u < NT*NK*64; u += 512)
    Bsm4[u] = Bg4[u];
  __syncthreads();

  #pragma unroll
  for (int ct = 0; ct < CTW; ++ct) {
    int nt = cg*CTW + ct;
    #pragma unroll
    for (int kc = 0; kc < NK; ++kc) {
      BU b; b.u = Bsm4[(nt*NK + kc)*64 + lane];
      acc[0][ct] = __builtin_amdgcn_mfma_f32_16x16x32_bf16(af[0][kc], b.s, acc[0][ct], 0, 0, 0);
      acc[1][ct] = __builtin_amdgcn_mfma_f32_16x16x32_bf16(af[1][kc], b.s, acc[1][ct], 0, 0, 0);
    }
  }

  #pragma unroll
  for (int rt = 0; rt < 2; ++rt) {
    #pragma unroll
    for (int ct = 0; ct < CTW; ++ct) {
      #pragma unroll
      for (int q = 0; q < 4; ++q) {
        int gr = row0 + rbase + rt*16 + lkb*4 + q;
        if (gr >= rowsReal) continue;
        int o = (cg*CTW + ct)*16 + lrow;
        int a = gr/DIV;
        float val = acc[rt][ct][q]*norm;
        float w = fb(wenvbf[(size_t)a*224 + WCOL + o]);
        val *= w*0.22360679774997896f;
        peout[(size_t)gr*N + o] = bf(val);
      }
    }
  }
}

// ---------------------------------------------------------------------------
// t0 chunked-pipeline GEMM with fused input build (x0 from nodef/edgef) and
// fused P0 epilogue.
// ---------------------------------------------------------------------------
constexpr int T0SMB = 55808;

template<int C>
__device__ __forceinline__ void t0_phase(int e, int tid, int lane, int cg,
                                         int rbase, int lkb,
                                         const short8 (&af)[2][6],
                                         f32x4 (&acc)[2][7],
                                         const float* coefsm,
                                         uint4* Bsm4, const uint4* Bg4,
                                         uint4& rg0, uint4& rg1, uint4& rg2) {
  fastbar();
  const bool hasNext = !(e == 8 && C == 3);
  if (hasNext) {
    int ne = e + (C == 3 ? 1 : 0);
    int nc = (C + 1) & 3;
    const uint4* s = Bg4 + (size_t)ne*6144 + (size_t)nc*1536;
    rg0 = s[tid]; rg1 = s[tid + 512]; rg2 = s[tid + 1024];
  }
  float cf[2][4];
  #pragma unroll
  for (int rt = 0; rt < 2; ++rt)
    #pragma unroll
    for (int q = 0; q < 4; ++q)
      cf[rt][q] = coefsm[(rbase + rt*16 + lkb*4 + q)*9 + e];
  union BU { uint4 u; short8 s; };
  const uint4* bb = Bsm4 + (C & 1)*1536;
  {
    f32x4 z0 = {0.f,0.f,0.f,0.f}, z1 = {0.f,0.f,0.f,0.f};
    #pragma unroll
    for (int kc = 0; kc < 6; ++kc) {
      BU b; b.u = bb[(cg*6 + kc)*64 + lane];
      z0 = __builtin_amdgcn_mfma_f32_16x16x32_bf16(af[0][kc], b.s, z0, 0, 0, 0);
      z1 = __builtin_amdgcn_mfma_f32_16x16x32_bf16(af[1][kc], b.s, z1, 0, 0, 0);
    }
    #pragma unroll
    for (int q = 0; q < 4; ++q) {
      acc[0][2*C][q] += cf[0][q]*z0[q];
      acc[1][2*C][q] += cf[1][q]*z1[q];
    }
  }
  if constexpr (2*C + 1 < 7) {
    f32x4 z0 = {0.f,0.f,0.f,0.f}, z1 = {0.f,0.f,0.f,0.f};
    #pragma unroll
    for (int kc = 0; kc < 6; ++kc) {
      BU b; b.u = bb[((2 + cg)*6 + kc)*64 + lane];
      z0 = __builtin_amdgcn_mfma_f32_16x16x32_bf16(af[0][kc], b.s, z0, 0, 0, 0);
      z1 = __builtin_amdgcn_mfma_f32_16x16x32_bf16(af[1][kc], b.s, z1, 0, 0, 0);
    }
    #pragma unroll
    for (int q = 0; q < 4; ++q) {
      acc[0][2*C + 1][q] += cf[0][q]*z0[q];
      acc[1][2*C + 1][q] += cf[1][q]*z1[q];
    }
  }
  fastbar();
  if (hasNext) {
    uint4* d = Bsm4 + ((C + 1) & 1)*1536;
    d[tid] = rg0; d[tid + 512] = rg1; d[tid + 1024] = rg2;
  }
}

__global__ __launch_bounds__(512, 2)
void t0c_k(const float* __restrict__ nodef, const float* __restrict__ edgef,
           const int* __restrict__ eidx, const int* __restrict__ act,
           const ushort* __restrict__ Bpk, const ushort* __restrict__ Bp0,
           const float* __restrict__ coefg, const float* __restrict__ bp0f,
           const ushort* __restrict__ wenvbf,
           ushort* __restrict__ t0act, ushort* __restrict__ pe0) {
  extern __shared__ char smraw[];
  __shared__ int cenl[128];
  ushort* Asm = (ushort*)smraw;
  float* coefsm = (float*)(smraw + 51200);
  uint4* Bsm4 = (uint4*)smraw;
  const uint4* Bg4 = (const uint4*)Bpk;

  const int tid = threadIdx.x;
  const int row0 = blockIdx.x*128;

  if (tid < 128) {
    int gr = row0 + tid;
    cenl[tid] = (gr < kE) ? eidx[act[gr]] : 0;
  }
  __syncthreads();

  for (int u = tid; u < 128*24; u += 512) {
    int r = u/24, g = u - r*24;
    int c0 = g*8;
    int gr = row0 + r;
    uint4 v = {0u,0u,0u,0u};
    if (gr < kE) {
      const float* s = (g < 16) ? (nodef + (size_t)cenl[r]*kNFD + c0)
                                : (edgef + (size_t)gr*240 + (c0 - 128));
      float4 f0 = *(const float4*)s;
      float4 f1 = *(const float4*)(s + 4);
      v.x = pk2(f0.x, f0.y); v.y = pk2(f0.z, f0.w);
      v.z = pk2(f1.x, f1.y); v.w = pk2(f1.z, f1.w);
    }
    *(uint4*)(&Asm[r*200 + c0]) = v;
  }
  for (int u = tid; u < 128*9; u += 512) {
    int r = u/9, e = u - r*9;
    coefsm[r*9 + e] = coefg[(size_t)(row0 + r)*9 + e];
  }
  __syncthreads();

  const int lane = tid & 63, wid = tid >> 6;
  const int cg = wid & 1, rg = wid >> 1;
  const int rbase = rg*32;
  const int lrow = lane & 15, lkb = lane >> 4;

  short8 af[2][6];
  #pragma unroll
  for (int rt = 0; rt < 2; ++rt)
    #pragma unroll
    for (int kc = 0; kc < 6; ++kc)
      af[rt][kc] = *(const short8*)(&Asm[(rbase + rt*16 + lrow)*200 + kc*32 + lkb*8]);

  f32x4 acc[2][7];
  #pragma unroll
  for (int rt = 0; rt < 2; ++rt)
    #pragma unroll
    for (int ct = 0; ct < 7; ++ct)
      acc[rt][ct] = f32x4{0.f,0.f,0.f,0.f};

  __syncthreads();

  uint4 rg0, rg1, rg2;
  { const uint4* s = Bg4; rg0 = s[tid]; rg1 = s[tid + 512]; rg2 = s[tid + 1024]; }
  { uint4* d = Bsm4;      d[tid] = rg0; d[tid + 512] = rg1; d[tid + 1024] = rg2; }

  for (int e = 0; e < 9; ++e) {
    t0_phase<0>(e, tid, lane, cg, rbase, lkb, af, acc, coefsm, Bsm4, Bg4, rg0, rg1, rg2);
    t0_phase<1>(e, tid, lane, cg, rbase, lkb, af, acc, coefsm, Bsm4, Bg4, rg0, rg1, rg2);
    t0_phase<2>(e, tid, lane, cg, rbase, lkb, af, acc, coefsm, Bsm4, Bg4, rg0, rg1, rg2);
    t0_phase<3>(e, tid, lane, cg, rbase, lkb, af, acc, coefsm, Bsm4, Bg4, rg0, rg1, rg2);
  }

  ushort* A2 = (ushort*)smraw;
  #pragma unroll
  for (int rt = 0; rt < 2; ++rt) {
    #pragma unroll
    for (int ct = 0; ct < 7; ++ct) {
      int o = (2*ct + cg)*16 + lrow;
      #pragma unroll
      for (int q = 0; q < 4; ++q) {
        int rloc = rbase + rt*16 + lkb*4 + q;
        int gr = row0 + rloc;
        float val = acc[rt][ct][q]*0.07216878364870323f;
        if (o < 128) {
          A2[rloc*136 + o] = bf(val/(1.f + __expf(-val)));
        } else if (gr < kE) {
          t0act[(size_t)gr*224 + o] = bf(1.f/(1.f + __expf(-val)));
        }
      }
    }
  }
  fastbar();

  short8 af2[2][4];
  #pragma unroll
  for (int rt = 0; rt < 2; ++rt)
    #pragma unroll
    for (int kc = 0; kc < 4; ++kc)
      af2[rt][kc] = *(const short8*)(&A2[(rbase + rt*16 + lrow)*136 + kc*32 + lkb*8]);

  union BU { uint4 u; short8 s; };
  const uint4* Bg0 = (const uint4*)Bp0;
  f32x4 acc2[2][4];
  #pragma unroll
  for (int rt = 0; rt < 2; ++rt)
    #pragma unroll
    for (int ct = 0; ct < 4; ++ct)
      acc2[rt][ct] = f32x4{0.f,0.f,0.f,0.f};

  #pragma unroll
  for (int ct = 0; ct < 4; ++ct) {
    int nt = cg*4 + ct;
    #pragma unroll
    for (int kc = 0; kc < 4; ++kc) {
      BU b; b.u = Bg0[(nt*4 + kc)*64 + lane];
      acc2[0][ct] = __builtin_amdgcn_mfma_f32_16x16x32_bf16(af2[0][kc], b.s, acc2[0][ct], 0, 0, 0);
      acc2[1][ct] = __builtin_amdgcn_mfma_f32_16x16x32_bf16(af2[1][kc], b.s, acc2[1][ct], 0, 0, 0);
    }
  }

  #pragma unroll
  for (int rt = 0; rt < 2; ++rt) {
    #pragma unroll
    for (int ct = 0; ct < 4; ++ct) {
      int o = (cg*4 + ct)*16 + lrow;
      float bia = bp0f[o];
      #pragma unroll
      for (int q = 0; q < 4; ++q) {
        int gr = row0 + rbase + rt*16 + lkb*4 + q;
        if (gr >= kE) continue;
        float v = acc2[rt][ct][q]*0.08838834764831845f + bia;
        v *= fb(wenvbf[(size_t)gr*224 + o])*0.22360679774997896f;
        pe0[(size_t)gr*128 + o] = bf(v);
      }
    }
  }
}

// ---------------------------------------------------------------------------
// y1/y2 chunked-pipeline GEMM with FUSED input build.
// ---------------------------------------------------------------------------
constexpr int ych_smbytes(int K1, int NK, int NT) {
  int a = 128*(K1 + 8)*2;
  int b = 2*NT*NK*1024;
  int u = a > b ? a : b;
  return u + 128*9*4;
}

template<int DIV, int K1, int NK, int NT, int FUSE>
__global__ __launch_bounds__(512, 2)
void ychunk_k(const float* __restrict__ nodef, const float* __restrict__ edgef,
              const float* __restrict__ Dm, const int* __restrict__ eidx,
              const int* __restrict__ act, const ushort* __restrict__ Bpk,
              const float* __restrict__ coefg, int rowsReal, float norm,
              ushort* __restrict__ outbf) {
  constexpr int CTW = NT/2;
  constexpr int N   = NT*16;
  constexpr int LDA = K1 + 8;
  constexpr int ABYTES = 128*LDA*2;
  constexpr int BBYTES = 2*NT*NK*1024;
  constexpr int UNI = (ABYTES > BBYTES) ? ABYTES : BBYTES;
  constexpr int NB4 = NT*NK*64;
  constexpr int DSTR = (FUSE == 1) ? 9 : 25;

  extern __shared__ char smraw[];
  ushort* Asm = (ushort*)smraw;
  float* coefsm = (float*)(smraw + UNI);
  uint4* Bsm4 = (uint4*)smraw;
  const uint4* Bg4 = (const uint4*)Bpk;

  const int tid = threadIdx.x;
  const int row0 = blockIdx.x*128;

  constexpr int C8 = K1/8;
  for (int u = tid; u < 128*C8; u += 512) {
    int r = u / C8, c8 = u - r*C8;
    int c0 = c8*8;
    int gr = row0 + r;
    uint4 v = {0u,0u,0u,0u};
    if (gr < rowsReal) {
      int a = gr/DIV, mm = gr - a*DIV;
      int cen = eidx[act[a]];
      const float* dd = Dm + (size_t)a*DSTR + mm*DIV;
      if constexpr (FUSE == 1) {
        const float* s = (c8 < 8) ? (nodef + (size_t)cen*kNFD + 128 + c0*3)
                                  : (edgef + (size_t)a*240 + 64 + (c0 - 64)*3);
        float ld[24];
        #pragma unroll
        for (int q = 0; q < 6; ++q)
          *(float4*)(ld + q*4) = *(const float4*)(s + q*4);
        float d0 = dd[0], d1 = dd[1], d2 = dd[2];
        float ov[8];
        #pragma unroll
        for (int j = 0; j < 8; ++j)
          ov[j] = d0*ld[3*j] + d1*ld[3*j + 1] + d2*ld[3*j + 2];
        v.x = pk2(ov[0], ov[1]); v.y = pk2(ov[2], ov[3]);
        v.z = pk2(ov[4], ov[5]); v.w = pk2(ov[6], ov[7]);
      } else {
        if (c0 < 48) {
          const float* s = (c0 < 32) ? (nodef + (size_t)cen*kNFD + 320 + c0*5)
                                     : (edgef + (size_t)a*240 + 160 + (c0 - 32)*5);
          float ld[40];
          #pragma unroll
          for (int q = 0; q < 10; ++q)
            *(float4*)(ld + q*4) = *(const float4*)(s + q*4);
          float d0 = dd[0], d1 = dd[1], d2 = dd[2], d3 = dd[3], d4 = dd[4];
          float ov[8];
          #pragma unroll
          for (int j = 0; j < 8; ++j)
            ov[j] = d0*ld[5*j] + d1*ld[5*j+1] + d2*ld[5*j+2] + d3*ld[5*j+3] + d4*ld[5*j+4];
          v.x = pk2(ov[0], ov[1]); v.y = pk2(ov[2], ov[3]);
          v.z = pk2(ov[4], ov[5]); v.w = pk2(ov[6], ov[7]);
        }
      }
    }
    *(uint4*)(&Asm[r*LDA + c0]) = v;
  }
  for (int u = tid; u < 128*9; u += 512) {
    int r = u/9, e = u - r*9;
    int a = (row0 + r)/DIV;
    coefsm[r*9 + e] = coefg[(size_t)a*9 + e];
  }
  __syncthreads();

  const int lane = tid & 63, wid = tid >> 6;
  const int cg = wid & 1, rg = wid >> 1;
  const int rbase = rg*32;
  const int lrow = lane & 15, lkb = lane >> 4;

  short8 af[2][NK];
  #pragma unroll
  for (int rt = 0; rt < 2; ++rt)
    #pragma unroll
    for (int kc = 0; kc < NK; ++kc)
      af[rt][kc] = *(const short8*)(&Asm[(rbase + rt*16 + lrow)*LDA + kc*32 + lkb*8]);

  f32x4 acc[2][CTW];
  #pragma unroll
  for (int rt = 0; rt < 2; ++rt)
    #pragma unroll
    for (int ct = 0; ct < CTW; ++ct)
      acc[rt][ct] = f32x4{0.f,0.f,0.f,0.f};

  __syncthreads();

  union BU { uint4 u; short8 s; };
  uint4 pf0, pf1;

  if (tid < NB4) pf0 = Bg4[tid];
  if constexpr (NB4 > 512) { if (tid + 512 < NB4) pf1 = Bg4[tid + 512]; }
  if (tid < NB4) Bsm4[tid] = pf0;
  if constexpr (NB4 > 512) { if (tid + 512 < NB4) Bsm4[tid + 512] = pf1; }

  for (int e = 0; e < 9; ++e) {
    fastbar();
    if (e + 1 < 9) {
      const uint4* s = Bg4 + (size_t)(e + 1)*NB4;
      if (tid < NB4) pf0 = s[tid];
      if constexpr (NB4 > 512) { if (tid + 512 < NB4) pf1 = s[tid + 512]; }
    }
    float cf[2][4];
    #pragma unroll
    for (int rt = 0; rt < 2; ++rt)
      #pragma unroll
      for (int q = 0; q < 4; ++q)
        cf[rt][q] = coefsm[(rbase + rt*16 + lkb*4 + q)*9 + e];
    const uint4* bb = Bsm4 + (e & 1)*NB4;
    #pragma unroll
    for (int ct = 0; ct < CTW; ++ct) {
      int nt = cg*CTW + ct;
      f32x4 z0 = {0.f,0.f,0.f,0.f}, z1 = {0.f,0.f,0.f,0.f};
      #pragma unroll
      for (int kc = 0; kc < NK; ++kc) {
        BU b; b.u = bb[(nt*NK + kc)*64 + lane];
        z0 = __builtin_amdgcn_mfma_f32_16x16x32_bf16(af[0][kc], b.s, z0, 0, 0, 0);
        z1 = __builtin_amdgcn_mfma_f32_16x16x32_bf16(af[1][kc], b.s, z1, 0, 0, 0);
      }
      #pragma unroll
      for (int q = 0; q < 4; ++q) {
        acc[0][ct][q] += cf[0][q]*z0[q];
        acc[1][ct][q] += cf[1][q]*z1[q];
      }
    }
    fastbar();
    if (e + 1 < 9) {
      uint4* d = Bsm4 + ((e + 1) & 1)*NB4;
      if (tid < NB4) d[tid] = pf0;
      if constexpr (NB4 > 512) { if (tid + 512 < NB4) d[tid + 512] = pf1; }
    }
  }

  #pragma unroll
  for (int rt = 0; rt < 2; ++rt) {
    #pragma unroll
    for (int ct = 0; ct < CTW; ++ct) {
      #pragma unroll
      for (int q = 0; q < 4; ++q) {
        int gr = row0 + rbase + rt*16 + lkb*4 + q;
        if (gr >= rowsReal) continue;
        int o = (cg*CTW + ct)*16 + lrow;
        outbf[(size_t)gr*N + o] = bf(acc[rt][ct][q]*norm);
      }
    }
  }
}

// ---------------------------------------------------------------------------
// Fused CSR gather + node finalize (unchanged).
// ---------------------------------------------------------------------------
__global__ __launch_bounds__(256)
void gather_k(const float* __restrict__ nodef, const float* __restrict__ onehot,
              const float* __restrict__ Woh0, const float* __restrict__ Woh1,
              const float* __restrict__ Woh2,
              const int* __restrict__ rowptr, const int* __restrict__ elist,
              const ushort* __restrict__ pe0, const ushort* __restrict__ pe1,
              const ushort* __restrict__ pe2, float* __restrict__ out) {
  __shared__ int tn;
  const int n = blockIdx.x;
  const int t = threadIdx.x;
  if (t < kNT && onehot[(size_t)n*kNT + t] > 0.5f) tn = t;
  __syncthreads();
  const int ty = tn;
  const int r0 = rowptr[n], r1 = rowptr[n + 1];
  const float c_old = 0.8944271909999159f;
  const float c_new = 0.4472135954999579f;
  const float invs  = 0.10259783520851541f;

  for (int j = t; j < kNFD; j += 256) {
    int kind, row_m, col;
    if (j < 128)       { kind = 0; row_m = 0; col = j; }
    else if (j < 320)  { int jj = j - 128; col = jj/3; row_m = jj - col*3; kind = 1; }
    else               { int jj = j - 320; col = jj/5; row_m = jj - col*5; kind = 2; }

    float s = 0.f;
    for (int d = r0; d < r1; ++d) {
      int e = elist[d];
      ushort v;
      if (kind == 0)      v = pe0[(size_t)e*128 + col];
      else if (kind == 1) v = pe1[((size_t)e*3 + row_m)*64 + col];
      else                v = pe2[((size_t)e*5 + row_m)*32 + col];
      s += fb(v);
    }

    size_t idx = (size_t)n*kNFD + j;
    float h = c_old*nodef[idx] + c_new*s;
    float f;
    if (j < 128)      f = Woh0[j*kNT + ty];
    else if (j < 320) f = Woh1[((j - 128)/3)*kNT + ty];
    else              f = Woh2[((j - 320)/5)*kNT + ty];
    out[idx] = h*(1.f + f*invs);
  }
}

// workspace layout (bytes)
constexpr size_t OFF_CNT  = 0;
constexpr size_t OFF_CUR  = 40000;
constexpr size_t OFF_RP   = 80000;
constexpr size_t OFF_EL   = 120064;
constexpr size_t OFF_PACK = 1000000;
constexpr size_t OFF_COEF = 19200000;
constexpr size_t OFF_MGL  = 26402304;
constexpr size_t OFF_PE0  = 168031232;
constexpr size_t OFF_X2R  = 219264000;    // pe1
constexpr size_t OFF_WENV = 347272192;
constexpr size_t OFF_T0A  = 436900864;
constexpr size_t OFF_Y1   = 526529536;    // y1; after P1: pe2
constexpr size_t OFF_Y2   = 603354112;    // y2

} // namespace

extern "C" void kernel_launch(void* const* d_in, const int* in_sizes, int n_in,
                              void* d_out, int out_size, void* d_ws, size_t ws_size,
                              hipStream_t stream) {
  (void)in_sizes; (void)n_in; (void)out_size; (void)ws_size;
  const float* latents = (const float*)d_in[0];
  const float* nodef   = (const float*)d_in[1];
  const float* edgef   = (const float*)d_in[2];
  const float* mg      = (const float*)d_in[4];
  const float* D1      = (const float*)d_in[5];
  const float* D2      = (const float*)d_in[6];
  const float* onehot  = (const float*)d_in[7];
  const float* Wg      = (const float*)d_in[8];
  const float* Wm      = (const float*)d_in[9];
  const float* W0e     = (const float*)d_in[10];
  const float* W0s     = (const float*)d_in[11];
  const float* W1e     = (const float*)d_in[12];
  const float* W1s     = (const float*)d_in[13];
  const float* W2e     = (const float*)d_in[14];
  const float* W2s     = (const float*)d_in[15];
  const float* Wp0     = (const float*)d_in[16];
  const float* bp0     = (const float*)d_in[17];
  const float* Wp1     = (const float*)d_in[18];
  const float* Wp2     = (const float*)d_in[19];
  const float* Wenv    = (const float*)d_in[20];
  const float* Woh0    = (const float*)d_in[21];
  const float* Woh1    = (const float*)d_in[22];
  const float* Woh2    = (const float*)d_in[23];
  const int* eidx      = (const int*)d_in[25];
  const int* act       = (const int*)d_in[26];

  char* ws = (char*)d_ws;
  int*    cnt   = (int*)(ws + OFF_CNT);
  int*    cur   = (int*)(ws + OFF_CUR);
  int*    rp    = (int*)(ws + OFF_RP);
  int*    el    = (int*)(ws + OFF_EL);
  ushort* pk    = (ushort*)(ws + OFF_PACK);
  float*  coef  = (float*)(ws + OFF_COEF);
  float*  mgl   = (float*)(ws + OFF_MGL);
  ushort* wenv  = (ushort*)(ws + OFF_WENV);
  ushort* t0act = (ushort*)(ws + OFF_T0A);
  ushort* pe0   = (ushort*)(ws + OFF_PE0);
  ushort* pe1   = (ushort*)(ws + OFF_X2R);
  ushort* pe2   = (ushort*)(ws + OFF_Y1);
  ushort* y1    = (ushort*)(ws + OFF_Y1);
  ushort* y2    = (ushort*)(ws + OFF_Y2);
  float*  out   = (float*)d_out;

  // ---- CSR build ----
  hipMemsetAsync(cnt, 0, kN*sizeof(int), stream);
  hist_k<<<(kE + 255)/256, 256, 0, stream>>>(eidx, act, cnt);
  scan_k<<<1, 256, 0, stream>>>(cnt, rp, cur);
  scatter_k<<<(kE + 255)/256, 256, 0, stream>>>(eidx, act, cur, el);

  pack_k<<<(PKTOT + 255)/256, 256, 0, stream>>>(W0e, W0s, W1e, W1s, W2e, W2s,
                                                Wenv, Wp0, Wp1, Wp2, pk);
  mgl_k<<<1, 64, 0, stream>>>(mg, Wm, mgl);

  // gates only (x0/x1r/x2r staging fused into consumers)
  coef_k<<<kE/32, 256, 0, stream>>>(latents, mgl, Wg, act, coef);

  // wenv = latents[act] @ Wenv / sqrt(128)
  {
    auto kp = gemm_k<1,128,4,224,1,0,true>;
    int smb = gemm_smbytes(128,4,224,1);
    hipFuncSetAttribute((const void*)kp, hipFuncAttributeMaxDynamicSharedMemorySize, smb);
    kp<<<1563, 512, smb, stream>>>(
        nullptr, latents, act, 128, pk + PKENV, nullptr, kE, 0.08838834764831845f,
        wenv, nullptr, nullptr, 0);
  }
  // y1 = mix1 with fused rotated-input build
  {
    auto kp = ychunk_k<3,96,3,4,1>;
    int smb = ych_smbytes(96,3,4);
    hipFuncSetAttribute((const void*)kp, hipFuncAttributeMaxDynamicSharedMemorySize, smb);
    kp<<<4688, 512, smb, stream>>>(
        nodef, edgef, D1, eidx, act, pk + PK1, coef, 3*kE,
        0.10206207261596577f, y1);
  }
  // y2 = mix2 with fused rotated-input build
  {
    auto kp = ychunk_k<5,64,2,2,2>;
    int smb = ych_smbytes(64,2,2);
    hipFuncSetAttribute((const void*)kp, hipFuncAttributeMaxDynamicSharedMemorySize, smb);
    kp<<<7813, 512, smb, stream>>>(
        nodef, edgef, D2, eidx, act, pk + PK2, coef, 5*kE,
        0.14433756729740643f, y2);
  }

  // t0 = mix0 with fused input build + fused P0 epilogue
  {
    hipFuncSetAttribute((const void*)t0c_k,
                        hipFuncAttributeMaxDynamicSharedMemorySize, T0SMB);
    t0c_k<<<1563, 512, T0SMB, stream>>>(nodef, edgef, eidx, act,
                                        pk + PK0, pk + PKP0, coef,
                                        bp0, wenv, t0act, pe0);
  }

  // P1 with fused rotate-back/gating -> pe1
  {
    auto kp = pv_k<1>;
    int smb = gemm_smbytes(64,2,64,1);
    hipFuncSetAttribute((const void*)kp, hipFuncAttributeMaxDynamicSharedMemorySize, smb);
    kp<<<4688, 512, smb, stream>>>(
        y1, t0act, D1, pk + PKP1, 3*kE, 0.125f, wenv, pe1);
  }
  // P2 with fused rotate-back/gating -> pe2
  {
    auto kp = pv_k<2>;
    int smb = gemm_smbytes(32,1,32,1);
    hipFuncSetAttribute((const void*)kp, hipFuncAttributeMaxDynamicSharedMemorySize, smb);
    kp<<<7813, 512, smb, stream>>>(
        y2, t0act, D2, pk + PKP2, 5*kE, 0.17677669529663687f, wenv, pe2);
  }

  gather_k<<<kN, 256, 0, stream>>>(nodef, onehot, Woh0, Woh1, Woh2,
                                   rp, el, pe0, pe1, pe2, out);
}